// Round 5
// baseline (428.381 us; speedup 1.0000x reference)
//
#include <hip/hip_runtime.h>

// Problem: B=32, C=17, H=256, W=256 fp32.
// out = 0.5 * ( sum(m1?d:0)/sum(m1) + sum(m2?d:0)/(sum(m2)*C) )
//   m1 = target>0 per element; m2 = any(m1 over C) per (b,h,w); d = |input-target|.
//
// Single-pass strategy: one flat contiguous sweep of inp+tgt (285 MB, the
// minimum) computes s1/c1/S_all and ballots the per-pixel "any channel > 0"
// bitmask into 256 KB of d_ws. s2 = S_all - sum over NON-m2 pixels (~16 of 2M
// for N(0,1) data, p=2^-17) which a tiny fixup kernel gathers directly.

typedef unsigned long long u64;
typedef unsigned int u32;

#define N_CH       17
#define QPP        16384               // float4-quads per (b,c) plane = HW/4
#define N_QUADS    (32 * N_CH * QPP)   // 8,912,896 flat float4s
#define GRID1      2048
#define STRIDE     (GRID1 * 256)
#define ITERS      17                  // GRID1*256*ITERS == N_QUADS exactly
#define N_GROUPS   8192                // 32 batches * 256 pixel-groups
#define MASK_WORDS (N_GROUPS * 4)      // 32768 u64 = 256 KiB
#define SLOT_OFF   (MASK_WORDS * 8)
#define N_PIX      2097152u            // 32 * 65536 pixels

struct Slot { float s1, sall; u32 c1, pad; };

__global__ __launch_bounds__(256) void mask_zero(u64* __restrict__ mask) {
    mask[blockIdx.x * 256 + threadIdx.x] = 0ULL;   // grid 128 -> 32768 words
}

// Main: flat contiguous dual-stream sweep with depth-2 prefetch. Per wave-iter:
// 2 global_load_dwordx4 (next) in flight while processing current; 4 ballots
// pack 256 pixels' (t>0) bits; lanes 0-3 atomicOr into the group's mask words.
__global__ __launch_bounds__(256, 8) void heat_sweep(
    const float* __restrict__ inp, const float* __restrict__ tgt,
    u64* __restrict__ mask, Slot* __restrict__ slots) {

    const float4* __restrict__ t4 = (const float4*)tgt;
    const float4* __restrict__ x4 = (const float4*)inp;

    const int lane = threadIdx.x & 63;
    int f = blockIdx.x * 256 + threadIdx.x;

    float s1 = 0.f, sall = 0.f;
    u32 c1 = 0u;

    float4 t = t4[f];
    float4 x = x4[f];

    #pragma unroll 1
    for (int it = 0; it < ITERS; ++it) {
        float4 tc = t, xc = x;
        const int fc = f;
        if (it + 1 < ITERS) {            // prefetch next tile
            f += STRIDE;
            t = t4[f];
            x = x4[f];
        }

        float d0 = fabsf(xc.x - tc.x);
        float d1 = fabsf(xc.y - tc.y);
        float d2 = fabsf(xc.z - tc.z);
        float d3 = fabsf(xc.w - tc.w);
        sall += (d0 + d1) + (d2 + d3);

        bool p0 = tc.x > 0.f, p1 = tc.y > 0.f, p2 = tc.z > 0.f, p3 = tc.w > 0.f;
        s1 += p0 ? d0 : 0.f;  c1 += p0 ? 1u : 0u;
        s1 += p1 ? d1 : 0.f;  c1 += p1 ? 1u : 0u;
        s1 += p2 ? d2 : 0.f;  c1 += p2 ? 1u : 0u;
        s1 += p3 ? d3 : 0.f;  c1 += p3 ? 1u : 0u;

        u64 b0 = __ballot(p0);
        u64 b1 = __ballot(p1);
        u64 b2 = __ballot(p2);
        u64 b3 = __ballot(p3);

        int plane = fc >> 14;                       // fc / QPP
        int b = plane / N_CH;                       // magic-mul div
        int grp = (b << 8) + ((fc & (QPP - 1)) >> 6);  // wave-uniform
        if (lane < 4) {
            u64 w = (lane == 0) ? b0 : (lane == 1) ? b1 : (lane == 2) ? b2 : b3;
            if (w) atomicOr(&mask[(size_t)grp * 4 + lane], w);
        }
    }

    // Intra-wave butterfly reduction (wave = 64 on gfx950)
    #pragma unroll
    for (int off = 32; off > 0; off >>= 1) {
        s1   += __shfl_down(s1, off);
        sall += __shfl_down(sall, off);
        c1   += __shfl_down(c1, off);
    }
    __shared__ float ls1[4], lsa[4];
    __shared__ u32 lc1[4];
    const int wave = threadIdx.x >> 6;
    if (lane == 0) { ls1[wave] = s1; lsa[wave] = sall; lc1[wave] = c1; }
    __syncthreads();
    if (threadIdx.x == 0) {
        Slot sl;
        sl.s1   = ls1[0] + ls1[1] + ls1[2] + ls1[3];
        sl.sall = lsa[0] + lsa[1] + lsa[2] + lsa[3];
        sl.c1   = lc1[0] + lc1[1] + lc1[2] + lc1[3];
        sl.pad  = 0u;
        slots[blockIdx.x] = sl;
    }
}

// Fixup: one block. Sums the 2048 slots; scans the 32768 mask words for ZERO
// bits (pixels with no positive channel — expected ~16 total); gathers those
// pixels' 17 |x-t| values directly (L3-hot) and subtracts from S_all.
__global__ __launch_bounds__(256) void fixup(
    const float* __restrict__ inp, const float* __restrict__ tgt,
    const u64* __restrict__ mask, const Slot* __restrict__ slots,
    float* __restrict__ out) {

    const int tid = threadIdx.x;
    float s1 = 0.f, sall = 0.f;
    u32 c1 = 0u;
    for (int i = tid; i < GRID1; i += 256) {
        Slot sl = slots[i];
        s1 += sl.s1; sall += sl.sall; c1 += sl.c1;
    }

    float sub = 0.f;
    u32 nz = 0u;
    for (int wi = tid; wi < MASK_WORDS; wi += 256) {
        u64 z = ~mask[wi];
        if (z) {
            const int g = wi >> 2;          // group index
            const int j = wi & 3;           // component within quad
            const int b = g >> 8;           // batch
            const int baseq = (g & 255) << 6;  // first quad of group in plane
            nz += (u32)__popcll(z);
            while (z) {
                int l = __builtin_ctzll(z);
                z &= z - 1;
                int pix = ((baseq + l) << 2) + j;     // pixel index in plane
                size_t base = ((size_t)b * N_CH) << 16;
                #pragma unroll
                for (int c = 0; c < N_CH; ++c) {
                    size_t off = base + ((size_t)c << 16) + (size_t)pix;
                    sub += fabsf(inp[off] - tgt[off]);
                }
            }
        }
    }

    const int lane = tid & 63;
    const int wave = tid >> 6;
    #pragma unroll
    for (int off = 32; off > 0; off >>= 1) {
        s1   += __shfl_down(s1, off);
        sall += __shfl_down(sall, off);
        sub  += __shfl_down(sub, off);
        c1   += __shfl_down(c1, off);
        nz   += __shfl_down(nz, off);
    }
    __shared__ float ls1[4], lsa[4], lsb[4];
    __shared__ u32 lc1[4], lnz[4];
    if (lane == 0) {
        ls1[wave] = s1; lsa[wave] = sall; lsb[wave] = sub;
        lc1[wave] = c1; lnz[wave] = nz;
    }
    __syncthreads();
    if (tid == 0) {
        float S1   = ls1[0] + ls1[1] + ls1[2] + ls1[3];
        float SALL = lsa[0] + lsa[1] + lsa[2] + lsa[3];
        float SUB  = lsb[0] + lsb[1] + lsb[2] + lsb[3];
        u32   C1   = lc1[0] + lc1[1] + lc1[2] + lc1[3];
        u32   NZ   = lnz[0] + lnz[1] + lnz[2] + lnz[3];
        float S2 = SALL - SUB;
        float C2 = (float)(N_PIX - NZ) * (float)N_CH;   // sum(m2) * C
        float mean1 = S1 / (float)C1;
        float mean2 = S2 / C2;
        out[0] = 0.5f * (mean1 + mean2);
    }
}

extern "C" void kernel_launch(void* const* d_in, const int* in_sizes, int n_in,
                              void* d_out, int out_size, void* d_ws, size_t ws_size,
                              hipStream_t stream) {
    const float* inp = (const float*)d_in[0];
    const float* tgt = (const float*)d_in[1];
    // d_in[2] (masks) and d_in[3] (hull) are unused by the forward pass.
    float* out = (float*)d_out;
    u64* mask = (u64*)d_ws;                          // 256 KiB
    Slot* slots = (Slot*)((char*)d_ws + SLOT_OFF);   // 32 KiB

    mask_zero<<<128, 256, 0, stream>>>(mask);
    heat_sweep<<<GRID1, 256, 0, stream>>>(inp, tgt, mask, slots);
    fixup<<<1, 256, 0, stream>>>(inp, tgt, mask, slots, out);
}

// Round 7
// 361.443 us; speedup vs baseline: 1.1852x; 1.1852x over previous
//
#include <hip/hip_runtime.h>

// Problem: B=32, C=17, H=256, W=256 fp32.
// out = 0.5 * ( sum(m1?d:0)/sum(m1) + sum(m2?d:0)/(sum(m2)*C) )
//   m1 = target>0 per element; m2 = any(m1 over C) per (b,h,w); d = |input-target|.
//
// Single-pass: one sweep of inp+tgt (285 MB minimum) computes s1/c1/S_all and
// ballots the per-pixel "any channel > 0" bitmask into 256 KB of d_ws.
// s2 = S_all - sum over NON-m2 pixels (~16 of 2M for N(0,1), p=2^-17), which
// the fixup kernel gathers directly.
//
// R7 = R6 intent with the compile fix: __builtin_nontemporal_load needs a
// native clang vector type, not HIP's float4 class. Block-contiguous
// sequential sweep (each block owns one contiguous 69.6 KB span per tensor,
// +4 KB/iter) + nontemporal loads.

typedef unsigned long long u64;
typedef unsigned int u32;
typedef float f4 __attribute__((ext_vector_type(4)));   // native vec for nt-load

#define N_CH       17
#define QPP        16384               // float4-quads per (b,c) plane = HW/4
#define Q_TOTAL    (32 * N_CH * QPP)   // 8,912,896 flat float4s
#define GRID1      2048
#define QPB_BLK    (Q_TOTAL / GRID1)   // 4352 float4s per block (contiguous)
#define ITERS      (QPB_BLK / 256)     // 17
#define N_GROUPS   8192                // 32 batches * 256 pixel-groups
#define MASK_WORDS (N_GROUPS * 4)      // 32768 u64 = 256 KiB
#define SLOT_OFF   (MASK_WORDS * 8)
#define N_PIX      2097152u            // 32 * 65536 pixels

struct Slot { float s1, sall; u32 c1, pad; };

__global__ __launch_bounds__(256) void mask_zero(u64* __restrict__ mask) {
    mask[blockIdx.x * 256 + threadIdx.x] = 0ULL;   // grid 128 -> 32768 words
}

// Main: block-contiguous sequential dual-stream sweep, depth-2 prefetch,
// nontemporal loads. Ballots pack 256 pixels' (t>0) bits per block-iter;
// lanes 0-3 atomicOr into the group's mask words.
__global__ __launch_bounds__(256, 8) void heat_sweep(
    const float* __restrict__ inp, const float* __restrict__ tgt,
    u64* __restrict__ mask, Slot* __restrict__ slots) {

    const f4* __restrict__ t4 = (const f4*)tgt;
    const f4* __restrict__ x4 = (const f4*)inp;

    const int lane = threadIdx.x & 63;
    int f = blockIdx.x * QPB_BLK + threadIdx.x;

    float s1 = 0.f, sall = 0.f;
    u32 c1 = 0u;

    f4 t = __builtin_nontemporal_load(t4 + f);
    f4 x = __builtin_nontemporal_load(x4 + f);

    #pragma unroll 1
    for (int it = 0; it < ITERS; ++it) {
        f4 tc = t, xc = x;
        const int fc = f;
        if (it + 1 < ITERS) {            // prefetch next 4 KB tile (sequential)
            f += 256;
            t = __builtin_nontemporal_load(t4 + f);
            x = __builtin_nontemporal_load(x4 + f);
        }

        float d0 = fabsf(xc.x - tc.x);
        float d1 = fabsf(xc.y - tc.y);
        float d2 = fabsf(xc.z - tc.z);
        float d3 = fabsf(xc.w - tc.w);
        sall += (d0 + d1) + (d2 + d3);

        bool p0 = tc.x > 0.f, p1 = tc.y > 0.f, p2 = tc.z > 0.f, p3 = tc.w > 0.f;
        s1 += p0 ? d0 : 0.f;  c1 += p0 ? 1u : 0u;
        s1 += p1 ? d1 : 0.f;  c1 += p1 ? 1u : 0u;
        s1 += p2 ? d2 : 0.f;  c1 += p2 ? 1u : 0u;
        s1 += p3 ? d3 : 0.f;  c1 += p3 ? 1u : 0u;

        u64 b0 = __ballot(p0);
        u64 b1 = __ballot(p1);
        u64 b2 = __ballot(p2);
        u64 b3 = __ballot(p3);

        // Wave-uniform group index: wave spans 64 aligned quads, planes are
        // 16384-quad aligned, so fc>>6 / fc>>14 are uniform across the wave.
        int plane = fc >> 14;
        int b = plane / N_CH;                          // magic-mul div
        int grp = (b << 8) + ((fc & (QPP - 1)) >> 6);
        if (lane < 4) {
            u64 w = (lane == 0) ? b0 : (lane == 1) ? b1 : (lane == 2) ? b2 : b3;
            if (w) atomicOr(&mask[(size_t)grp * 4 + lane], w);
        }
    }

    // Intra-wave butterfly reduction (wave = 64 on gfx950)
    #pragma unroll
    for (int off = 32; off > 0; off >>= 1) {
        s1   += __shfl_down(s1, off);
        sall += __shfl_down(sall, off);
        c1   += __shfl_down(c1, off);
    }
    __shared__ float ls1[4], lsa[4];
    __shared__ u32 lc1[4];
    const int wave = threadIdx.x >> 6;
    if (lane == 0) { ls1[wave] = s1; lsa[wave] = sall; lc1[wave] = c1; }
    __syncthreads();
    if (threadIdx.x == 0) {
        Slot sl;
        sl.s1   = ls1[0] + ls1[1] + ls1[2] + ls1[3];
        sl.sall = lsa[0] + lsa[1] + lsa[2] + lsa[3];
        sl.c1   = lc1[0] + lc1[1] + lc1[2] + lc1[3];
        sl.pad  = 0u;
        slots[blockIdx.x] = sl;
    }
}

// Fixup: one block. Sums the 2048 slots; scans the 32768 mask words for ZERO
// bits (pixels with no positive channel — expected ~16 total); gathers those
// pixels' 17 |x-t| values and subtracts from S_all. Mask scan uses ulonglong2
// loads + unroll so 4+ independent loads stay in flight (R5's scalar scan was
// serial-latency-bound).
__global__ __launch_bounds__(256) void fixup(
    const float* __restrict__ inp, const float* __restrict__ tgt,
    const u64* __restrict__ mask, const Slot* __restrict__ slots,
    float* __restrict__ out) {

    const int tid = threadIdx.x;
    float s1 = 0.f, sall = 0.f;
    u32 c1 = 0u;
    #pragma unroll 4
    for (int i = tid; i < GRID1; i += 256) {
        Slot sl = slots[i];
        s1 += sl.s1; sall += sl.sall; c1 += sl.c1;
    }

    float sub = 0.f;
    u32 nz = 0u;
    const ulonglong2* __restrict__ mv = (const ulonglong2*)mask;
    #pragma unroll 4
    for (int v = tid; v < MASK_WORDS / 2; v += 256) {
        ulonglong2 w = mv[v];
        u64 zz[2] = { ~w.x, ~w.y };
        #pragma unroll
        for (int h = 0; h < 2; ++h) {
            u64 z = zz[h];
            if (z) {
                const int wi = 2 * v + h;
                const int g = wi >> 2;             // group index
                const int j = wi & 3;              // component within quad
                const int b = g >> 8;              // batch
                const int baseq = (g & 255) << 6;  // first quad of group
                nz += (u32)__popcll(z);
                while (z) {
                    int l = __builtin_ctzll(z);
                    z &= z - 1;
                    int pix = ((baseq + l) << 2) + j;
                    size_t base = ((size_t)b * N_CH) << 16;
                    #pragma unroll
                    for (int c = 0; c < N_CH; ++c) {
                        size_t off = base + ((size_t)c << 16) + (size_t)pix;
                        sub += fabsf(inp[off] - tgt[off]);
                    }
                }
            }
        }
    }

    const int lane = tid & 63;
    const int wave = tid >> 6;
    #pragma unroll
    for (int off = 32; off > 0; off >>= 1) {
        s1   += __shfl_down(s1, off);
        sall += __shfl_down(sall, off);
        sub  += __shfl_down(sub, off);
        c1   += __shfl_down(c1, off);
        nz   += __shfl_down(nz, off);
    }
    __shared__ float ls1[4], lsa[4], lsb[4];
    __shared__ u32 lc1[4], lnz[4];
    if (lane == 0) {
        ls1[wave] = s1; lsa[wave] = sall; lsb[wave] = sub;
        lc1[wave] = c1; lnz[wave] = nz;
    }
    __syncthreads();
    if (tid == 0) {
        float S1   = ls1[0] + ls1[1] + ls1[2] + ls1[3];
        float SALL = lsa[0] + lsa[1] + lsa[2] + lsa[3];
        float SUB  = lsb[0] + lsb[1] + lsb[2] + lsb[3];
        u32   C1   = lc1[0] + lc1[1] + lc1[2] + lc1[3];
        u32   NZ   = lnz[0] + lnz[1] + lnz[2] + lnz[3];
        float S2 = SALL - SUB;
        float C2 = (float)(N_PIX - NZ) * (float)N_CH;   // sum(m2) * C
        float mean1 = S1 / (float)C1;
        float mean2 = S2 / C2;
        out[0] = 0.5f * (mean1 + mean2);
    }
}

extern "C" void kernel_launch(void* const* d_in, const int* in_sizes, int n_in,
                              void* d_out, int out_size, void* d_ws, size_t ws_size,
                              hipStream_t stream) {
    const float* inp = (const float*)d_in[0];
    const float* tgt = (const float*)d_in[1];
    // d_in[2] (masks) and d_in[3] (hull) are unused by the forward pass.
    float* out = (float*)d_out;
    u64* mask = (u64*)d_ws;                          // 256 KiB
    Slot* slots = (Slot*)((char*)d_ws + SLOT_OFF);   // 32 KiB

    mask_zero<<<128, 256, 0, stream>>>(mask);
    heat_sweep<<<GRID1, 256, 0, stream>>>(inp, tgt, mask, slots);
    fixup<<<1, 256, 0, stream>>>(inp, tgt, mask, slots, out);
}